// Round 8
// baseline (93.037 us; speedup 1.0000x reference)
//
#include <hip/hip_runtime.h>
#include <hip/hip_bf16.h>

typedef __attribute__((ext_vector_type(8))) short short8_t;
typedef __attribute__((ext_vector_type(4))) float f32x4;

#define BATCH 16
#define CIN   512
#define COUT  512
#define TT    4096

// pack 2 f32 -> u32 of 2 bf16 (RNE); pairs into v_cvt_pk_bf16_f32
__device__ __forceinline__ uint pk2(float a, float b) {
    ushort lo = __builtin_bit_cast(ushort, __float2bfloat16(a));
    ushort hi = __builtin_bit_cast(ushort, __float2bfloat16(b));
    return (uint)lo | ((uint)hi << 16);
}

// ---------------------------------------------------------------------------
// Pre-pass: W (fp32 [512][512]) -> bf16 MFMA-fragment order:
//   Wb[bm][ksg][g][r][8k], bm=m>>4, r=m&15, ksg=k>>5, g=(k>>3)&3
// One A fragment = one coalesced dwordx4 (verified numerically R5-R7).
// ---------------------------------------------------------------------------
extern "C" __global__ __launch_bounds__(256)
void wconv(const float* __restrict__ W, ushort* __restrict__ Wb)
{
    const int i  = blockIdx.x * 256 + threadIdx.x;   // [0, 65536)
    const int m  = i >> 7;
    const int k0 = (i & 127) * 4;
    const float4 v = *(const float4*)(W + (size_t)m * CIN + k0);
    const int bm = m >> 4, r = m & 15;
    const int ksg = k0 >> 5, g = (k0 >> 3) & 3, k7 = k0 & 7;
    uint2 q;
    q.x = pk2(v.x, v.y);
    q.y = pk2(v.z, v.w);
    *(uint2*)&Wb[(size_t)bm * 8192 + ksg * 512 + g * 128 + r * 8 + k7] = q;
}

// ---------------------------------------------------------------------------
// Main GEMM: block tile 256m x 32t, FULL K=512 resident in LDS as bf16.
//   Prologue: each block converts its whole B panel (512k x 32t) fp32->bf16
//             into LDS once (straight-line; load->cvt sinking is harmless).
//   K-loop:   16 iters, barrier-free: 4 A-frag global loads (Wb, L2-hot),
//             2 B-frag ds_read_b128, 8 MFMA per wave per iter.
// LDS layout: LB[ko][slot][8k] ushort, ko=k>>3 (64 rows of 512B),
//   slot = t ^ (ko&7)  -> writes exactly 2-way (free), frag reads per-16-lane
//   contiguous 256B (0-conflict pattern, measured in R5/R7).
// 4 waves, wave tile 64m x 32t (mi=4, ni=2, acc=32 VGPR).
// ---------------------------------------------------------------------------
template<bool WSB>
__global__ __launch_bounds__(256)
void conv2x1_gemm(const float* __restrict__ pre, const float* __restrict__ W,
                  const ushort* __restrict__ Wb,
                  const float* __restrict__ bias, float* __restrict__ out)
{
    __shared__ alignas(16) ushort LB[64 * 32 * 8];   // 32 KiB

    const int tid  = threadIdx.x;
    const int lane = tid & 63;
    const int wv   = tid >> 6;          // wave = 64m strip [0,4)
    const int g    = lane >> 4;
    const int l15  = lane & 15;

    // XCD-chunked bijective swizzle (4096 = 8*512). Adjacent ids share the
    // B panel (mblk 0/1) and stay on one XCD's L2.
    const int id   = ((blockIdx.x & 7) << 9) | (blockIdx.x >> 3);
    const int mblk = id & 1;
    const int ti   = (id >> 1) & 127;
    const int bb   = id >> 8;

    const int m0 = mblk << 8;   // {0, 256}
    const int t0 = ti << 5;     // [0,4096) step 32

    const float* preB   = pre + (size_t)bb * ((size_t)CIN * TT);
    const int    bmBase = (m0 >> 4) + wv * 4;

    // ---------------- prologue: full B panel fp32 -> bf16 LDS ----------------
    // 512 slots of (8k x 4t); thread handles 2 slots.
#pragma unroll
    for (int it = 0; it < 2; ++it) {
        const int slot = it * 256 + tid;
        const int ko   = slot >> 3;      // [0,64)
        const int tg   = slot & 7;       // t = 4*tg .. +3
        float4 v[8];
#pragma unroll
        for (int j = 0; j < 8; ++j)
            v[j] = *(const float4*)(preB + (size_t)(ko * 8 + j) * TT + t0 + tg * 4);
#pragma unroll
        for (int jj = 0; jj < 4; ++jj) {
            uint4 q;
            q.x = pk2(((const float*)&v[0])[jj], ((const float*)&v[1])[jj]);
            q.y = pk2(((const float*)&v[2])[jj], ((const float*)&v[3])[jj]);
            q.z = pk2(((const float*)&v[4])[jj], ((const float*)&v[5])[jj]);
            q.w = pk2(((const float*)&v[6])[jj], ((const float*)&v[7])[jj]);
            const int sl = (tg * 4 + jj) ^ (ko & 7);
            *(uint4*)&LB[ko * 256 + sl * 8] = q;
        }
    }
    __syncthreads();   // the only barrier in the kernel

    // ---------------- K-loop: barrier-free, LDS + L2 only ----------------
    f32x4 acc[4][2];
#pragma unroll
    for (int i = 0; i < 4; ++i)
#pragma unroll
        for (int j = 0; j < 2; ++j) acc[i][j] = (f32x4)0.0f;

#pragma unroll 4
    for (int it = 0; it < 16; ++it) {
        short8_t af[4], bf[2];
        if constexpr (WSB) {
#pragma unroll
            for (int mi = 0; mi < 4; ++mi)
                af[mi] = *(const short8_t*)(Wb + (size_t)(bmBase + mi) * 8192
                                            + it * 512 + g * 128 + l15 * 8);
        } else {
#pragma unroll
            for (int mi = 0; mi < 4; ++mi) {
                const float* ab = W + (size_t)(m0 + wv * 64 + mi * 16 + l15) * CIN
                                  + it * 32 + g * 8;
                const float4 u0 = *(const float4*)ab;
                const float4 u1 = *(const float4*)(ab + 4);
                uint4 qq;
                qq.x = pk2(u0.x, u0.y); qq.y = pk2(u0.z, u0.w);
                qq.z = pk2(u1.x, u1.y); qq.w = pk2(u1.z, u1.w);
                af[mi] = __builtin_bit_cast(short8_t, qq);
            }
        }
#pragma unroll
        for (int ni = 0; ni < 2; ++ni) {
            const int ko = it * 4 + g;
            const int sl = (ni * 16 + l15) ^ (ko & 7);
            bf[ni] = *(const short8_t*)&LB[ko * 256 + sl * 8];
        }
#pragma unroll
        for (int mi = 0; mi < 4; ++mi)
#pragma unroll
            for (int ni = 0; ni < 2; ++ni)
                acc[mi][ni] = __builtin_amdgcn_mfma_f32_16x16x32_bf16(af[mi], bf[ni], acc[mi][ni], 0, 0, 0);
    }

    // ---------------- epilogue: out = 2*(acc + bias) ----------------
    const int orow = m0 + wv * 64 + g * 4;   // + mi*16 + r
    float bv[4][4];
#pragma unroll
    for (int mi = 0; mi < 4; ++mi)
#pragma unroll
        for (int r = 0; r < 4; ++r)
            bv[mi][r] = bias[orow + mi * 16 + r];

    float* outB = out + (size_t)bb * ((size_t)COUT * TT);
#pragma unroll
    for (int mi = 0; mi < 4; ++mi) {
#pragma unroll
        for (int ni = 0; ni < 2; ++ni) {
            const int t = t0 + ni * 16 + l15;
#pragma unroll
            for (int r = 0; r < 4; ++r) {
                const int o = orow + mi * 16 + r;
                outB[(size_t)o * TT + t] = 2.0f * (acc[mi][ni][r] + bv[mi][r]);
            }
        }
    }
}

extern "C" void kernel_launch(void* const* d_in, const int* in_sizes, int n_in,
                              void* d_out, int out_size, void* d_ws, size_t ws_size,
                              hipStream_t stream)
{
    const float* pre  = (const float*)d_in[0];   // [16, 512, 4096] fp32
    const float* Wp   = (const float*)d_in[1];   // [512, 512] fp32
    const float* bias = (const float*)d_in[2];   // [512] fp32
    float* out = (float*)d_out;                  // [16, 512, 4096] fp32

    const bool usews = (ws_size >= (size_t)(COUT * CIN * sizeof(ushort)));  // 512 KiB

    const dim3 grid(BATCH * 2 * 128);   // 16 b x 2 m-tiles x 128 t-tiles = 4096
    const dim3 block(256);

    if (usews) {
        ushort* Wb = (ushort*)d_ws;
        hipLaunchKernelGGL(wconv, dim3(256), dim3(256), 0, stream, Wp, Wb);
        hipLaunchKernelGGL((conv2x1_gemm<true>), grid, block, 0, stream,
                           pre, Wp, Wb, bias, out);
    } else {
        hipLaunchKernelGGL((conv2x1_gemm<false>), grid, block, 0, stream,
                           pre, Wp, (const ushort*)nullptr, bias, out);
    }
}